// Round 1
// baseline (1532.391 us; speedup 1.0000x reference)
//
#include <hip/hip_runtime.h>
#include <hip/hip_bf16.h>

#define NNODES 100000
#define NEDGES 3200000
#define INF 128
#define HID 32

// ---------------- degree histograms ----------------
__global__ void k_deg(const int* __restrict__ src, const int* __restrict__ dst,
                      int* __restrict__ outdeg, int* __restrict__ indeg) {
    int i = blockIdx.x * 256 + threadIdx.x;   // grid = E/256 exact
    atomicAdd(&outdeg[src[i]], 1);
    atomicAdd(&indeg[dst[i]], 1);
}

// ---------------- norms + row offsets ----------------
__global__ void k_norm(const int* __restrict__ outdeg, const int* __restrict__ indeg,
                       float* __restrict__ out_norm, float* __restrict__ in_norm,
                       int* __restrict__ rowstart, int* __restrict__ cursor,
                       int* __restrict__ counter) {
    int n = blockIdx.x * 256 + threadIdx.x;
    if (n < NNODES) {
        int od = outdeg[n], id = indeg[n];
        out_norm[n] = rsqrtf((float)(od > 1 ? od : 1));
        in_norm[n]  = rsqrtf((float)(id > 1 ? id : 1));
        int s = atomicAdd(counter, id);
        rowstart[n] = s;
        cursor[n]   = s;
    }
}

// ---------------- CSR scatter (col = src sorted by dst, arbitrary in-row order) ---
__global__ void k_scatter(const int* __restrict__ src, const int* __restrict__ dst,
                          int* __restrict__ cursor, int* __restrict__ col) {
    int i = blockIdx.x * 256 + threadIdx.x;   // grid = E/256 exact
    int d = dst[i];
    int pos = atomicAdd(&cursor[d], 1);
    col[pos] = src[i];
}

// ---------------- conv1 dense part: t[n] = out_norm[n] * (x[n] @ W1) ----------------
__global__ void k_gemm1(const float* __restrict__ x, const float* __restrict__ W1,
                        const float* __restrict__ out_norm, float* __restrict__ t) {
    __shared__ float wlds[INF * HID];          // 16 KB
    __shared__ float xlds[8][INF];             // 4 KB
    int tid = threadIdx.x;
    for (int i = tid; i < INF * HID; i += 256) wlds[i] = W1[i];
    int group = tid >> 5, lane = tid & 31;
    int row = blockIdx.x * 8 + group;          // grid = N/8 exact (12500)
    float4 xv = ((const float4*)(x + (size_t)row * INF))[lane];
    ((float4*)xlds[group])[lane] = xv;
    __syncthreads();
    float acc = 0.f;
#pragma unroll
    for (int k = 0; k < INF; ++k)
        acc += xlds[group][k] * wlds[k * HID + lane];
    t[(size_t)row * HID + lane] = acc * out_norm[row];
}

// ---------------- fused SpMM step ----------------
// acc = sum_{e in row(n)} gin[col[e]]; acc *= in_norm
// APPLY_W: res = b + acc @ W   else: res = acc + b
// FINAL:   gout = res          else: gout = res * out_norm (pre-scale for next step)
template<int APPLY_W, int FINAL>
__global__ void k_spmm(const float* __restrict__ gin, const int* __restrict__ rowstart,
                       const int* __restrict__ indeg, const int* __restrict__ col,
                       const float* __restrict__ in_norm, const float* __restrict__ out_norm,
                       const float* __restrict__ W, const float* __restrict__ bias,
                       float* __restrict__ gout) {
    __shared__ float wlds[HID * HID];          // 4 KB
    __shared__ float sh[8][HID];
    int tid = threadIdx.x, lane = tid & 31, group = tid >> 5;
    if (APPLY_W) {
        for (int i = tid; i < HID * HID; i += 256) wlds[i] = W[i];
        __syncthreads();
    }
    int n = blockIdx.x * 8 + group;            // grid = N/8 exact
    int start = rowstart[n];
    int deg   = indeg[n];
    float acc = 0.f;
    for (int base = 0; base < deg; base += 32) {
        int c = 0;
        if (base + lane < deg) c = col[start + base + lane];
        int m = deg - base; if (m > 32) m = 32;
        for (int j = 0; j < m; ++j) {
            int s = __shfl(c, j, 32);
            acc += gin[(size_t)s * HID + lane];
        }
    }
    acc *= in_norm[n];
    float res;
    if (APPLY_W) {
        sh[group][lane] = acc;                 // within-wave (32-lane group inside wave64)
        float o = bias[lane];
#pragma unroll
        for (int k = 0; k < HID; ++k)
            o += sh[group][k] * wlds[k * HID + lane];
        res = o;
    } else {
        res = acc + bias[lane];
    }
    if (FINAL) gout[(size_t)n * HID + lane] = res;
    else       gout[(size_t)n * HID + lane] = res * out_norm[n];
}

extern "C" void kernel_launch(void* const* d_in, const int* in_sizes, int n_in,
                              void* d_out, int out_size, void* d_ws, size_t ws_size,
                              hipStream_t stream) {
    const float* in_feat = (const float*)d_in[0];
    const float* W1      = (const float*)d_in[1];
    const float* b1      = (const float*)d_in[2];
    const float* W2      = (const float*)d_in[3];
    const float* b2      = (const float*)d_in[4];
    const int*   src     = (const int*)d_in[5];
    const int*   dst     = (const int*)d_in[6];
    float*       out     = (float*)d_out;

    const int N = NNODES, E = NEDGES;
    // workspace layout (all 4-byte units; every block 16B-aligned)
    int* outdeg   = (int*)d_ws;                 // N
    int* indeg    = outdeg + N;                 // N
    int* counter  = indeg + N;                  // 4 (use [0])
    int* rowstart = counter + 4;                // N
    int* cursor   = rowstart + N;               // N
    float* out_norm = (float*)(cursor + N);     // N
    float* in_norm  = out_norm + N;             // N
    int*   col      = (int*)(in_norm + N);      // E
    float* bufA     = (float*)(col + E);        // N*32
    float* bufB     = bufA + (size_t)N * HID;   // N*32
    size_t need = ((size_t)6 * N + 4 + E + (size_t)2 * N * HID) * 4;
    if (ws_size < need) return;                 // fail visibly rather than corrupt

    // zero outdeg, indeg, counter in one shot (contiguous)
    hipMemsetAsync(outdeg, 0, (size_t)(2 * N + 4) * sizeof(int), stream);

    k_deg    <<<E / 256, 256, 0, stream>>>(src, dst, outdeg, indeg);
    k_norm   <<<(N + 255) / 256, 256, 0, stream>>>(outdeg, indeg, out_norm, in_norm,
                                                   rowstart, cursor, counter);
    k_scatter<<<E / 256, 256, 0, stream>>>(src, dst, cursor, col);

    // conv1 dense projection (weight_first since 128>32)
    k_gemm1<<<N / 8, 256, 0, stream>>>(in_feat, W1, out_norm, bufA);

    // conv1 aggregate: bufA -> bufB, res = agg*in_norm + b1, pre-scaled by out_norm
    k_spmm<0, 0><<<N / 8, 256, 0, stream>>>(bufA, rowstart, indeg, col, in_norm,
                                            out_norm, W2, b1, bufB);

    // 6 middle convs: ping-pong B->A->B->...
    float* cur = bufB; float* nxt = bufA;
    for (int i = 0; i < 6; ++i) {
        k_spmm<1, 0><<<N / 8, 256, 0, stream>>>(cur, rowstart, indeg, col, in_norm,
                                                out_norm, W2, b2, nxt);
        float* tmp = cur; cur = nxt; nxt = tmp;
    }
    // final conv: cur -> out (no out_norm pre-scale, raw h)
    k_spmm<1, 1><<<N / 8, 256, 0, stream>>>(cur, rowstart, indeg, col, in_norm,
                                            out_norm, W2, b2, out);
}